// Round 3
// baseline (946.994 us; speedup 1.0000x reference)
//
#include <hip/hip_runtime.h>
#include <hip/hip_bf16.h>

// VirtualNodeDgl: pool = segment_sum(h, seg); vn_new = vn + relu((vn+pool)@W.T + b);
// h_new = h + vn_new[seg].  Outputs concatenated: [h_new (N*D), vn_new (M*D)].
// N=1e6, M=4096, D=128, seg sorted int32 (per harness: integer -> const int*).

#define D 128
#define D4 32  // D / 4 (float4 per row)

// ---------------- K1: per-graph pooled sum ----------------
// One block per graph. seg sorted -> binary search [start,end).
// 256 threads: lane c4 = t&31 owns float4 column, rowgroup rg = t>>5 (8 rows/iter).
__global__ __launch_bounds__(256) void pool_kernel(
    const float* __restrict__ h, const int* __restrict__ seg,
    float* __restrict__ pool, int N) {
  const int g = blockIdx.x;

  // lower_bound(seg, g) and lower_bound(seg, g+1) — wave-uniform scalar search
  int lo = 0, hi = N;
  while (lo < hi) { int mid = (lo + hi) >> 1; if (seg[mid] < g) lo = mid + 1; else hi = mid; }
  const int start = lo;
  hi = N;
  while (lo < hi) { int mid = (lo + hi) >> 1; if (seg[mid] < g + 1) lo = mid + 1; else hi = mid; }
  const int end = lo;

  const int t  = threadIdx.x;
  const int c4 = t & 31;
  const int rg = t >> 5;

  float4 acc = make_float4(0.f, 0.f, 0.f, 0.f);
  for (int r = start + rg; r < end; r += 8) {
    float4 v = reinterpret_cast<const float4*>(h + (size_t)r * D)[c4];
    acc.x += v.x; acc.y += v.y; acc.z += v.z; acc.w += v.w;
  }

  __shared__ float4 red[8][32];
  red[rg][c4] = acc;
  __syncthreads();
  if (t < 32) {
    float4 s = red[0][t];
    #pragma unroll
    for (int i = 1; i < 8; ++i) {
      float4 v = red[i][t];
      s.x += v.x; s.y += v.y; s.z += v.z; s.w += v.w;
    }
    reinterpret_cast<float4*>(pool + (size_t)g * D)[t] = s;
  }
}

// ---------------- K2: vn_new = vn + relu((vn+pool) @ W.T + b) ----------------
// Blocks of 16 rows. W staged in LDS [128][129] (+1 pad -> (c+k)%32 = 2-way, free).
__global__ __launch_bounds__(256) void fc_kernel(
    const float* __restrict__ vn_h, const float* __restrict__ pool,
    const float* __restrict__ W, const float* __restrict__ b,
    float* __restrict__ vn_new, int M) {
  __shared__ float Wl[D][D + 1];
  __shared__ float xr[2][D];

  const int t = threadIdx.x;
  for (int i = t; i < D * D; i += 256) {
    Wl[i >> 7][i & 127] = W[i];
  }

  const int c    = t & 127;   // output column
  const int rh   = t >> 7;    // 0/1: which of the 2 concurrent rows (wave-uniform)
  const int base = blockIdx.x * 16;
  const float bias = b[c];

  __syncthreads();

  for (int j = 0; j < 8; ++j) {
    const int r = base + j * 2 + rh;
    const bool ok = r < M;
    // stage x = vn_h + pool for rows (base+2j, base+2j+1)
    if (ok) xr[rh][c] = vn_h[(size_t)r * D + c] + pool[(size_t)r * D + c];
    __syncthreads();
    if (ok) {
      float acc = bias;
      #pragma unroll 8
      for (int k = 0; k < D; ++k) acc += xr[rh][k] * Wl[c][k];  // xr: wave-uniform broadcast
      const float relu = acc > 0.f ? acc : 0.f;
      vn_new[(size_t)r * D + c] = vn_h[(size_t)r * D + c] + relu;
    }
    __syncthreads();  // protect xr before next iteration overwrites
  }
}

// ---------------- K3: h_new = h + vn_new[seg] ----------------
// Grid-stride over float4 elements. 32 lanes per row -> seg read broadcast/L1-hit.
__global__ __launch_bounds__(256) void bcast_kernel(
    const float* __restrict__ h, const float* __restrict__ vn_new,
    const int* __restrict__ seg, float* __restrict__ out, int N) {
  const size_t total  = (size_t)N * D4;
  const size_t stride = (size_t)gridDim.x * blockDim.x;
  for (size_t idx = (size_t)blockIdx.x * blockDim.x + threadIdx.x; idx < total; idx += stride) {
    const size_t row = idx >> 5;
    const int    c4  = (int)(idx & 31);
    const int    g   = seg[row];
    float4 hv = reinterpret_cast<const float4*>(h)[idx];
    float4 vv = reinterpret_cast<const float4*>(vn_new + (size_t)g * D)[c4];
    hv.x += vv.x; hv.y += vv.y; hv.z += vv.z; hv.w += vv.w;
    reinterpret_cast<float4*>(out)[idx] = hv;
  }
}

extern "C" void kernel_launch(void* const* d_in, const int* in_sizes, int n_in,
                              void* d_out, int out_size, void* d_ws, size_t ws_size,
                              hipStream_t stream) {
  const float* h    = (const float*)d_in[0];   // [N, D]
  const float* vn_h = (const float*)d_in[1];   // [M, D]
  const int*   seg  = (const int*)  d_in[2];   // [N] sorted
  const float* W    = (const float*)d_in[3];   // [D, D]
  const float* b    = (const float*)d_in[4];   // [D]

  const int N = in_sizes[2];          // 1,000,000
  const int M = in_sizes[1] / D;      // 4096

  float* h_new  = (float*)d_out;                       // [N, D]
  float* vn_new = (float*)d_out + (size_t)N * D;       // [M, D]
  float* pool   = (float*)d_ws;                        // [M, D] scratch (2 MB)

  // K1: segment pooled sum (one block per graph)
  pool_kernel<<<M, 256, 0, stream>>>(h, seg, pool, N);

  // K2: FC + relu + residual on virtual nodes
  fc_kernel<<<(M + 15) / 16, 256, 0, stream>>>(vn_h, pool, W, b, vn_new, M);

  // K3: broadcast virtual node back to nodes
  const size_t total4 = (size_t)N * D4;
  int blocks = (int)((total4 + 255) / 256);
  if (blocks > 2048) blocks = 2048;
  bcast_kernel<<<blocks, 256, 0, stream>>>(h, vn_new, seg, h_new, N);
}